// Round 2
// baseline (132.914 us; speedup 1.0000x reference)
//
#include <hip/hip_runtime.h>
#include <stdint.h>

#define IN_DIM 4096

__global__ __launch_bounds__(256) void snn_step_kernel(
    const int*    __restrict__ x,    // (IN,1) int32 binary spikes
    const float4* __restrict__ W,    // (OUT,IN) f32, 4 elems per float4
    const float4* __restrict__ T,    // trace
    const float4* __restrict__ D,    // delay (small non-negative ints as f32)
    const float*  __restrict__ dtp,
    const float*  __restrict__ taup,
    const float*  __restrict__ alp,
    float4* __restrict__ O0,         // weight * spike_out
    float4* __restrict__ O1,         // trace_new
    int nvec)                        // OUT*IN/4
{
    const float k  = (*dtp) / (*taup);  // dt/tau
    const float al = *alp;

    const int stride = gridDim.x * blockDim.x;
    for (int v = blockIdx.x * blockDim.x + threadIdx.x; v < nvec; v += stride) {
        const int col = (v * 4) & (IN_DIM - 1);   // row-major, IN=4096 divisible by 4
        const int4   xv = *(const int4*)(x + col);
        const float4 wv = W[v];
        const float4 tv = T[v];
        const float4 dv = D[v];

        const float xf[4] = {(float)xv.x, (float)xv.y, (float)xv.z, (float)xv.w};
        const float wq[4] = {wv.x, wv.y, wv.z, wv.w};
        const float tq[4] = {tv.x, tv.y, tv.z, tv.w};
        const float dq[4] = {dv.x, dv.y, dv.z, dv.w};
        float oq[4], nq[4];

        #pragma unroll
        for (int q = 0; q < 4; ++q) {
            // trace_new = trace + k*(-trace + alpha*x)   (reference op order)
            const float u = al * xf[q] - tq[q];
            nq[q] = tq[q] + k * u;
            // spike = ((d>0 ? d-1 : d) == 1)  <=>  d == 2  (d is an exact small int)
            const float e = (dq[q] > 0.0f) ? dq[q] - 1.0f : dq[q];
            oq[q] = (e == 1.0f) ? wq[q] : 0.0f;
        }

        O0[v] = make_float4(oq[0], oq[1], oq[2], oq[3]);
        O1[v] = make_float4(nq[0], nq[1], nq[2], nq[3]);
    }
}

extern "C" void kernel_launch(void* const* d_in, const int* in_sizes, int n_in,
                              void* d_out, int out_size, void* d_ws, size_t ws_size,
                              hipStream_t stream) {
    // setup_inputs order: x, weight, trace, delay, delay_init(UNUSED), dt, tau_t, alpha_t
    const int*    x  = (const int*)d_in[0];
    const float4* W  = (const float4*)d_in[1];
    const float4* T  = (const float4*)d_in[2];
    const float4* D  = (const float4*)d_in[3];
    // d_in[4] = delay_init: dead in the reference (delay_new is deleted) — never read.
    const float*  dtp  = (const float*)d_in[5];
    const float*  taup = (const float*)d_in[6];
    const float*  alp  = (const float*)d_in[7];

    const int n_elems = in_sizes[1];        // OUT*IN = 33,554,432
    const int nvec    = n_elems / 4;        // 4 f32 per float4

    float4* O0 = (float4*)d_out;                    // output 0, flat f32
    float4* O1 = (float4*)((float*)d_out + n_elems); // output 1 follows

    const int block = 256;
    const int grid  = 2048;  // 256 CU x 8 blocks/CU, grid-stride
    snn_step_kernel<<<grid, block, 0, stream>>>(x, W, T, D, dtp, taup, alp, O0, O1, nvec);
}